// Round 2
// baseline (289.151 us; speedup 1.0000x reference)
//
#include <hip/hip_runtime.h>

#define BB 256
#define TT 256
#define CC 512
#define HH 64

typedef __bf16 bf16;
typedef __bf16 bf16x4 __attribute__((ext_vector_type(4)));
typedef __bf16 bf16x8 __attribute__((ext_vector_type(8)));
typedef float  f32x4  __attribute__((ext_vector_type(4)));

#define MFMA16(a, b, c) __builtin_amdgcn_mfma_f32_16x16x32_bf16((a), (b), (c), 0, 0, 0)

// ---------------------------------------------------------------------------
// K0: transpose fp32 weights into bf16 wt. slot0 = Wq, slot1 = Wk, slot2 = Wv.
// wt[n][k] so GEMM B-fragments (8 consecutive k at fixed n) are 16B loads.
// ---------------------------------------------------------------------------
__global__ __launch_bounds__(256) void wtrans(const float* __restrict__ Wk,
                                              const float* __restrict__ Wq,
                                              const float* __restrict__ Wv,
                                              bf16* __restrict__ wt) {
    int which = blockIdx.y;
    const float* W = (which == 0) ? Wq : (which == 1) ? Wk : Wv;
    int idx = blockIdx.x * 256 + threadIdx.x;   // 0..32767
    int k = idx >> 6, n = idx & 63;             // W is [C=512][H=64] row-major
    wt[which * (CC * HH) + n * CC + k] = (bf16)W[idx];
}

// ---------------------------------------------------------------------------
// K1: fused QKV GEMM. x:[65536,512] fp32 read once; N=192 (q|k|v) bf16 out.
// Mtile=128 (LDS bf16, +8 pad), BK=64. q gets the C^-0.5 scale folded in.
// v is written transposed [B, H, T] for the PV B-operand.
// ---------------------------------------------------------------------------
__global__ __launch_bounds__(256, 2) void qkv_gemm(const float* __restrict__ x,
                                                   const bf16* __restrict__ wt,
                                                   bf16* __restrict__ q,
                                                   bf16* __restrict__ k,
                                                   bf16* __restrict__ vt) {
    __shared__ bf16 xs[128 * 72];   // 72 = 64+8 pad
    const int tid  = threadIdx.x;
    const int wv   = tid >> 6;
    const int lane = tid & 63;
    const int quad = lane >> 4;
    const int l15  = lane & 15;
    const int mblk = blockIdx.x;    // 512 blocks x 128 rows

    f32x4 acc[2][12];
    #pragma unroll
    for (int mt = 0; mt < 2; ++mt)
        #pragma unroll
        for (int nt = 0; nt < 12; ++nt)
            acc[mt][nt] = (f32x4){0.f, 0.f, 0.f, 0.f};

    for (int kc = 0; kc < 8; ++kc) {
        __syncthreads();
        #pragma unroll
        for (int p = 0; p < 8; ++p) {           // 128 rows x 16 float4 = 2048 / 256 thr
            int c = p * 256 + tid;
            int row = c >> 4, c4 = c & 15;
            f32x4 xv = *(const f32x4*)(&x[(size_t)(mblk * 128 + row) * CC + kc * 64 + c4 * 4]);
            bf16x4 xb;
            #pragma unroll
            for (int j = 0; j < 4; ++j) xb[j] = (bf16)xv[j];
            *(bf16x4*)(&xs[row * 72 + c4 * 4]) = xb;
        }
        __syncthreads();

        bf16x8 af[2][2];
        #pragma unroll
        for (int mt = 0; mt < 2; ++mt)
            #pragma unroll
            for (int ks = 0; ks < 2; ++ks)
                af[mt][ks] = *(const bf16x8*)(&xs[(wv * 32 + mt * 16 + l15) * 72 + ks * 32 + quad * 8]);

        #pragma unroll
        for (int nt = 0; nt < 12; ++nt) {
            const bf16* wp = wt + (nt >> 2) * (CC * HH) + ((nt & 3) * 16 + l15) * CC + kc * 64 + quad * 8;
            bf16x8 b0 = *(const bf16x8*)(wp);
            bf16x8 b1 = *(const bf16x8*)(wp + 32);
            #pragma unroll
            for (int mt = 0; mt < 2; ++mt) {
                acc[mt][nt] = MFMA16(af[mt][0], b0, acc[mt][nt]);
                acc[mt][nt] = MFMA16(af[mt][1], b1, acc[mt][nt]);
            }
        }
    }

    const float scale = 0.044194173824159216f;  // 512^-0.5, folded into q
    #pragma unroll
    for (int mt = 0; mt < 2; ++mt) {
        int gt = mblk * 128 + wv * 32 + mt * 16 + quad * 4;   // + r
        #pragma unroll
        for (int nt = 0; nt < 12; ++nt) {
            int h = (nt & 3) * 16 + l15;
            int wch = nt >> 2;
            if (wch == 0) {
                #pragma unroll
                for (int r = 0; r < 4; ++r)
                    q[(gt + r) * HH + h] = (bf16)(acc[mt][nt][r] * scale);
            } else if (wch == 1) {
                #pragma unroll
                for (int r = 0; r < 4; ++r)
                    k[(gt + r) * HH + h] = (bf16)(acc[mt][nt][r]);
            } else {
                int bb = gt >> 8;       // Mtile=128 is batch-aligned
                int tloc = gt & 255;    // multiple of 4 -> 8B-aligned packed store
                bf16x4 pv;
                #pragma unroll
                for (int r = 0; r < 4; ++r) pv[r] = (bf16)(acc[mt][nt][r]);
                *(bf16x4*)(&vt[(bb * HH + h) * TT + tloc]) = pv;
            }
        }
    }
}

// ---------------------------------------------------------------------------
// K2: causal attention. grid (4, B); each wave owns one 16-row Q tile.
// S = q@k^T (scale pre-folded), causal mask, softmax via quad-group shuffles,
// P -> per-wave LDS (C-layout -> A-layout transform), PV with vt [B,H,T].
// Fully-masked column tiles are skipped (wave-uniform branch). fp32 out.
// ---------------------------------------------------------------------------
__global__ __launch_bounds__(256) void attn(const bf16* __restrict__ q,
                                            const bf16* __restrict__ k,
                                            const bf16* __restrict__ vt,
                                            float* __restrict__ out) {
    __shared__ bf16 pbuf[4][16 * 40];   // per-wave 16x32 chunk, stride 40
    const int tid  = threadIdx.x;
    const int wv   = tid >> 6;
    const int lane = tid & 63;
    const int quad = lane >> 4;
    const int l15  = lane & 15;
    const int b    = blockIdx.y;
    const int rowbase = blockIdx.x * 64 + wv * 16;
    const int ctmax   = rowbase >> 4;   // inclusive last live 16-col tile

    const bf16* qrow = q + (b * TT + rowbase + l15) * HH + quad * 8;
    bf16x8 aq0 = *(const bf16x8*)(qrow);
    bf16x8 aq1 = *(const bf16x8*)(qrow + 32);

    f32x4 sv[16];
    #pragma unroll
    for (int ct = 0; ct < 16; ++ct) {
        if (ct <= ctmax) {              // wave-uniform
            f32x4 a = (f32x4){0.f, 0.f, 0.f, 0.f};
            const bf16* kp = k + (b * TT + ct * 16 + l15) * HH + quad * 8;
            bf16x8 b0 = *(const bf16x8*)(kp);
            bf16x8 b1 = *(const bf16x8*)(kp + 32);
            a = MFMA16(aq0, b0, a);
            a = MFMA16(aq1, b1, a);
            int s = ct * 16 + l15;
            #pragma unroll
            for (int r = 0; r < 4; ++r) {
                int t = rowbase + quad * 4 + r;
                sv[ct][r] = (s <= t) ? a[r] : -3.0e38f;
            }
        }
    }

    float mx[4] = {-3.0e38f, -3.0e38f, -3.0e38f, -3.0e38f};
    #pragma unroll
    for (int ct = 0; ct < 16; ++ct)
        if (ct <= ctmax) {
            #pragma unroll
            for (int r = 0; r < 4; ++r) mx[r] = fmaxf(mx[r], sv[ct][r]);
        }
    #pragma unroll
    for (int off = 1; off <= 8; off <<= 1) {
        #pragma unroll
        for (int r = 0; r < 4; ++r) mx[r] = fmaxf(mx[r], __shfl_xor(mx[r], off));
    }

    float sm[4] = {0.f, 0.f, 0.f, 0.f};
    f32x4 o[4];
    #pragma unroll
    for (int nt = 0; nt < 4; ++nt) o[nt] = (f32x4){0.f, 0.f, 0.f, 0.f};
    bf16* pb = &pbuf[wv][0];

    #pragma unroll
    for (int ks2 = 0; ks2 < 8; ++ks2) {
        if (ks2 <= (ctmax >> 1)) {      // wave-uniform
            #pragma unroll
            for (int half = 0; half < 2; ++half) {
                int ct = ks2 * 2 + half;
                #pragma unroll
                for (int r = 0; r < 4; ++r) {
                    float e = 0.f;
                    if (ct <= ctmax) e = __expf(sv[ct][r] - mx[r]);
                    sm[r] += e;
                    pb[(quad * 4 + r) * 40 + half * 16 + l15] = (bf16)e;  // C-layout write
                }
            }
            asm volatile("" ::: "memory");  // keep ds_reads after ds_writes
            bf16x8 ap = *(const bf16x8*)(&pb[l15 * 40 + quad * 8]);       // A-layout read
            #pragma unroll
            for (int nt = 0; nt < 4; ++nt) {
                bf16x8 bv = *(const bf16x8*)(&vt[(b * HH + nt * 16 + l15) * TT + ks2 * 32 + quad * 8]);
                o[nt] = MFMA16(ap, bv, o[nt]);
            }
        }
    }

    #pragma unroll
    for (int off = 1; off <= 8; off <<= 1) {
        #pragma unroll
        for (int r = 0; r < 4; ++r) sm[r] += __shfl_xor(sm[r], off);
    }

    #pragma unroll
    for (int r = 0; r < 4; ++r) {
        float rinv = 1.0f / sm[r];
        int t = rowbase + quad * 4 + r;
        #pragma unroll
        for (int nt = 0; nt < 4; ++nt)
            out[((size_t)b * TT + t) * HH + nt * 16 + l15] = o[nt][r] * rinv;
    }
}

// ---------------------------------------------------------------------------
extern "C" void kernel_launch(void* const* d_in, const int* in_sizes, int n_in,
                              void* d_out, int out_size, void* d_ws, size_t ws_size,
                              hipStream_t stream) {
    const float* x  = (const float*)d_in[0];
    const float* Wk = (const float*)d_in[1];
    const float* Wq = (const float*)d_in[2];
    const float* Wv = (const float*)d_in[3];

    bf16* ws = (bf16*)d_ws;
    bf16* wt = ws;                                   // 3 * 512*64 = 98304 elems
    bf16* q  = ws + 3 * CC * HH;
    bf16* k  = q + (size_t)BB * TT * HH;             // 4194304 elems each
    bf16* vt = k + (size_t)BB * TT * HH;             // total ws ~25.4 MB bf16
    float* out = (float*)d_out;

    wtrans<<<dim3(128, 3), 256, 0, stream>>>(Wk, Wq, Wv, wt);
    qkv_gemm<<<dim3(512), 256, 0, stream>>>(x, wt, q, k, vt);
    attn<<<dim3(4, 256), 256, 0, stream>>>(q, k, vt, out);
}

// Round 3
// 266.443 us; speedup vs baseline: 1.0852x; 1.0852x over previous
//
#include <hip/hip_runtime.h>

#define BB 256
#define TT 256
#define CC 512
#define HH 64

typedef __bf16 bf16;
typedef __bf16 bf16x4 __attribute__((ext_vector_type(4)));
typedef __bf16 bf16x8 __attribute__((ext_vector_type(8)));
typedef float  f32x4  __attribute__((ext_vector_type(4)));

#define MFMA16(a, b, c) __builtin_amdgcn_mfma_f32_16x16x32_bf16((a), (b), (c), 0, 0, 0)

// ---------------------------------------------------------------------------
// K0: transpose fp32 weights into bf16 wt. slot0 = Wq, slot1 = Wk, slot2 = Wv.
// wt[n][k] so GEMM B-fragments (8 consecutive k at fixed n) are 16B loads.
// ---------------------------------------------------------------------------
__global__ __launch_bounds__(256) void wtrans(const float* __restrict__ Wk,
                                              const float* __restrict__ Wq,
                                              const float* __restrict__ Wv,
                                              bf16* __restrict__ wt) {
    int which = blockIdx.y;
    const float* W = (which == 0) ? Wq : (which == 1) ? Wk : Wv;
    int idx = blockIdx.x * 256 + threadIdx.x;   // 0..32767
    int k = idx >> 6, n = idx & 63;             // W is [C=512][H=64] row-major
    wt[which * (CC * HH) + n * CC + k] = (bf16)W[idx];
}

// ---------------------------------------------------------------------------
// K1: fused QKV GEMM, BARRIER-FREE. 2048 blocks x 64 threads (1 wave).
// Wave owns 32 rows x 192 cols; A-frags direct from global fp32 (cvt in reg),
// B-frags direct from global wt (L1/L2-hot, 192 KB total). No LDS, no syncs —
// loads pipeline freely across unrolled K chunks.
// q gets C^-0.5 folded in; v written transposed [B, H, T].
// ---------------------------------------------------------------------------
__global__ __launch_bounds__(64) void qkv_gemm(const float* __restrict__ x,
                                               const bf16* __restrict__ wt,
                                               bf16* __restrict__ q,
                                               bf16* __restrict__ k,
                                               bf16* __restrict__ vt) {
    const int lane = threadIdx.x;
    const int quad = lane >> 4;
    const int l15  = lane & 15;
    const int rows0 = blockIdx.x * 32;

    f32x4 acc[2][12];
    #pragma unroll
    for (int mt = 0; mt < 2; ++mt)
        #pragma unroll
        for (int nt = 0; nt < 12; ++nt)
            acc[mt][nt] = (f32x4){0.f, 0.f, 0.f, 0.f};

    const float* xp0 = x + (size_t)(rows0 + l15) * CC + quad * 8;
    const float* xp1 = xp0 + (size_t)16 * CC;
    const bf16*  wb  = wt + (size_t)l15 * CC + quad * 8;

    #pragma unroll 4
    for (int kc = 0; kc < 16; ++kc) {
        // A-fragments: 16x32 tiles, fp32 -> bf16 in registers
        f32x4 a00 = *(const f32x4*)(xp0 + kc * 32);
        f32x4 a01 = *(const f32x4*)(xp0 + kc * 32 + 4);
        f32x4 a10 = *(const f32x4*)(xp1 + kc * 32);
        f32x4 a11 = *(const f32x4*)(xp1 + kc * 32 + 4);
        bf16x8 af0, af1;
        #pragma unroll
        for (int j = 0; j < 4; ++j) {
            af0[j] = (bf16)a00[j]; af0[j + 4] = (bf16)a01[j];
            af1[j] = (bf16)a10[j]; af1[j + 4] = (bf16)a11[j];
        }
        #pragma unroll
        for (int nt = 0; nt < 12; ++nt) {
            bf16x8 bfr = *(const bf16x8*)(wb + (nt >> 2) * (CC * HH) + ((nt & 3) * 16) * CC + kc * 32);
            acc[0][nt] = MFMA16(af0, bfr, acc[0][nt]);
            acc[1][nt] = MFMA16(af1, bfr, acc[1][nt]);
        }
    }

    const float scale = 0.044194173824159216f;  // 512^-0.5, folded into q
    #pragma unroll
    for (int mt = 0; mt < 2; ++mt) {
        int gt = rows0 + mt * 16 + quad * 4;    // + r
        #pragma unroll
        for (int nt = 0; nt < 12; ++nt) {
            int h = (nt & 3) * 16 + l15;
            int wch = nt >> 2;
            if (wch == 0) {
                #pragma unroll
                for (int r = 0; r < 4; ++r)
                    q[(gt + r) * HH + h] = (bf16)(acc[mt][nt][r] * scale);
            } else if (wch == 1) {
                #pragma unroll
                for (int r = 0; r < 4; ++r)
                    k[(gt + r) * HH + h] = (bf16)(acc[mt][nt][r]);
            } else {
                int bb = gt >> 8;       // rows0 is 32-aligned -> same batch
                int tloc = gt & 255;    // multiple of 4 -> 8B-aligned packed store
                bf16x4 pv;
                #pragma unroll
                for (int r = 0; r < 4; ++r) pv[r] = (bf16)(acc[mt][nt][r]);
                *(bf16x4*)(&vt[(bb * HH + h) * TT + tloc]) = pv;
            }
        }
    }
}

// ---------------------------------------------------------------------------
// K2: causal attention, transposed-S formulation. grid (4, B) x 256 thr;
// each wave owns one 16-row Q tile.
//   S^T = MFMA(K-frag, Q-frag): C-layout col(l15)=qrow, row(quad*4+r)=s.
//   Softmax: in-lane max/sum over s + shfl_xor(16,32) across quads.
//   P^T -> per-wave LDS via packed ds_write_b64; PV: O^T = MFMA(V^T, P^T)
//   with ds_read_b128 B-frags; output packed global_store_dwordx4.
// All exp+writes batched before all reads+MFMAs (no serialized chain).
// ---------------------------------------------------------------------------
__global__ __launch_bounds__(256) void attn(const bf16* __restrict__ q,
                                            const bf16* __restrict__ k,
                                            const bf16* __restrict__ vt,
                                            float* __restrict__ out) {
    __shared__ bf16 pbuf[4][16 * 264];  // per-wave P^T: [qrow 16][s 256+8 pad]
    const int tid  = threadIdx.x;
    const int wv   = tid >> 6;
    const int lane = tid & 63;
    const int quad = lane >> 4;
    const int l15  = lane & 15;
    const int b    = blockIdx.y;
    const int rowbase = blockIdx.x * 64 + wv * 16;
    const int ctmax   = rowbase >> 4;   // inclusive last live 16-col s-tile

    // Q as B-operand: B[n=qrow=l15][k=h=quad*8+j]
    const bf16* qrow = q + (b * TT + rowbase + l15) * HH + quad * 8;
    bf16x8 bq0 = *(const bf16x8*)(qrow);
    bf16x8 bq1 = *(const bf16x8*)(qrow + 32);

    // Phase 1: all S^T tiles upfront (independent MFMAs)
    f32x4 sv[16];
    #pragma unroll
    for (int ct = 0; ct < 16; ++ct) {
        if (ct <= ctmax) {              // wave-uniform
            const bf16* kp = k + (b * TT + ct * 16 + l15) * HH + quad * 8;
            bf16x8 k0 = *(const bf16x8*)(kp);
            bf16x8 k1 = *(const bf16x8*)(kp + 32);
            f32x4 a = (f32x4){0.f, 0.f, 0.f, 0.f};
            a = MFMA16(k0, bq0, a);
            a = MFMA16(k1, bq1, a);
            int t = rowbase + l15;      // this lane's query row
            #pragma unroll
            for (int r = 0; r < 4; ++r) {
                int s = ct * 16 + quad * 4 + r;
                sv[ct][r] = (s <= t) ? a[r] : -3.0e38f;
            }
        }
    }

    // Phase 2: row max (per qrow = l15): in-lane + across quads
    float mx = -3.0e38f;
    #pragma unroll
    for (int ct = 0; ct < 16; ++ct)
        if (ct <= ctmax) {
            #pragma unroll
            for (int r = 0; r < 4; ++r) mx = fmaxf(mx, sv[ct][r]);
        }
    mx = fmaxf(mx, __shfl_xor(mx, 16));
    mx = fmaxf(mx, __shfl_xor(mx, 32));

    // Phase 3: exp, row-sum, batched packed P^T writes to LDS
    bf16* pb = &pbuf[wv][0];
    float sm = 0.f;
    #pragma unroll
    for (int ct = 0; ct < 16; ++ct) {
        if (ct <= ctmax) {              // wave-uniform
            bf16x4 ev;
            #pragma unroll
            for (int r = 0; r < 4; ++r) {
                float e = __expf(sv[ct][r] - mx);
                sm += e;
                ev[r] = (bf16)e;
            }
            *(bf16x4*)(&pb[l15 * 264 + ct * 16 + quad * 4]) = ev;
        }
    }
    if (!(ctmax & 1)) {                 // zero the dead half of the last 32-chunk
        int ctz = ctmax + 1;            // ctmax even -> ctz <= 15
        *(bf16x4*)(&pb[l15 * 264 + ctz * 16 + quad * 4]) = (bf16x4){(bf16)0.f, (bf16)0.f, (bf16)0.f, (bf16)0.f};
    }
    sm += __shfl_xor(sm, 16);
    sm += __shfl_xor(sm, 32);
    asm volatile("" ::: "memory");      // order ds_reads after ds_writes

    // Phase 4: PV — O^T = MFMA(V^T-frag, P^T-frag), all chains independent
    f32x4 o[4];
    #pragma unroll
    for (int ht = 0; ht < 4; ++ht) o[ht] = (f32x4){0.f, 0.f, 0.f, 0.f};
    #pragma unroll
    for (int ks2 = 0; ks2 < 8; ++ks2) {
        if (ks2 <= (ctmax >> 1)) {      // wave-uniform
            bf16x8 pf = *(const bf16x8*)(&pb[l15 * 264 + ks2 * 32 + quad * 8]);
            #pragma unroll
            for (int ht = 0; ht < 4; ++ht) {
                bf16x8 vf = *(const bf16x8*)(&vt[(b * HH + ht * 16 + l15) * TT + ks2 * 32 + quad * 8]);
                o[ht] = MFMA16(vf, pf, o[ht]);
            }
        }
    }

    // Epilogue: normalize, packed fp32 stores.
    // O^T C-layout: col(l15)=qrow, row(quad*4+r)=h within ht-tile.
    float rinv = 1.0f / sm;             // uniform across quads for fixed l15
    int t = rowbase + l15;
    #pragma unroll
    for (int ht = 0; ht < 4; ++ht) {
        f32x4 ov;
        #pragma unroll
        for (int r = 0; r < 4; ++r) ov[r] = o[ht][r] * rinv;
        *(f32x4*)(&out[((size_t)b * TT + t) * HH + ht * 16 + quad * 4]) = ov;
    }
}

// ---------------------------------------------------------------------------
extern "C" void kernel_launch(void* const* d_in, const int* in_sizes, int n_in,
                              void* d_out, int out_size, void* d_ws, size_t ws_size,
                              hipStream_t stream) {
    const float* x  = (const float*)d_in[0];
    const float* Wk = (const float*)d_in[1];
    const float* Wq = (const float*)d_in[2];
    const float* Wv = (const float*)d_in[3];

    bf16* ws = (bf16*)d_ws;
    bf16* wt = ws;                                   // 3 * 512*64 = 98304 elems
    bf16* q  = ws + 3 * CC * HH;
    bf16* k  = q + (size_t)BB * TT * HH;             // 4194304 elems each
    bf16* vt = k + (size_t)BB * TT * HH;             // total ws ~25.4 MB bf16
    float* out = (float*)d_out;

    wtrans<<<dim3(128, 3), 256, 0, stream>>>(Wk, Wq, Wv, wt);
    qkv_gemm<<<dim3(2048), 64, 0, stream>>>(x, wt, q, k, vt);
    attn<<<dim3(4, 256), 256, 0, stream>>>(q, k, vt, out);
}

// Round 4
// 238.036 us; speedup vs baseline: 1.2147x; 1.1193x over previous
//
#include <hip/hip_runtime.h>

#define BB 256
#define TT 256
#define CC 512
#define HH 64

typedef __bf16 bf16;
typedef __bf16 bf16x4 __attribute__((ext_vector_type(4)));
typedef __bf16 bf16x8 __attribute__((ext_vector_type(8)));
typedef float  f32x4  __attribute__((ext_vector_type(4)));

#define MFMA16(a, b, c) __builtin_amdgcn_mfma_f32_16x16x32_bf16((a), (b), (c), 0, 0, 0)

typedef __attribute__((address_space(1))) const void cas1_void;
typedef __attribute__((address_space(3))) void as3_void;
// Fire-and-forget global->LDS DMA, 16 B/lane. LDS dest = wave-uniform base + lane*16.
__device__ __forceinline__ void g2lds16(const void* g, void* l) {
    __builtin_amdgcn_global_load_lds((cas1_void*)g, (as3_void*)l, 16, 0, 0);
}

// ---------------------------------------------------------------------------
// K0: transpose fp32 weights into bf16 wt[which][n][k]. 4 k's per thread ->
// coalesced reads (consecutive n), packed 8B writes.
// ---------------------------------------------------------------------------
__global__ __launch_bounds__(256) void wtrans(const float* __restrict__ Wk,
                                              const float* __restrict__ Wq,
                                              const float* __restrict__ Wv,
                                              bf16* __restrict__ wt) {
    int which = blockIdx.y;
    const float* W = (which == 0) ? Wq : (which == 1) ? Wk : Wv;
    int idx = blockIdx.x * 256 + threadIdx.x;   // 0..8191
    int n = idx & 63, k4 = idx >> 6;            // k4: 0..127
    bf16x4 o;
    #pragma unroll
    for (int i = 0; i < 4; ++i) o[i] = (bf16)W[(k4 * 4 + i) * HH + n];
    *(bf16x4*)(&wt[which * (CC * HH) + n * CC + k4 * 4]) = o;
}

// ---------------------------------------------------------------------------
// K1: fused QKV GEMM, m97-style. 512 blocks x 256 thr; M-tile 128, BK=64 fp32.
// x staged via global_load_lds (8 fire-and-forget insts/chunk) into XOR-swizzled
// LDS (16B unit u of row r lives at u ^ (r&15)); wt B-frags batched into regs
// BEFORE the barrier so their latency hides under the x drain.
// ---------------------------------------------------------------------------
__global__ __launch_bounds__(256, 2) void qkv_gemm(const float* __restrict__ x,
                                                   const bf16* __restrict__ wt,
                                                   bf16* __restrict__ q,
                                                   bf16* __restrict__ k,
                                                   bf16* __restrict__ vt) {
    __shared__ float xs[128 * 64];      // 32 KB, swizzled, NO pad (DMA layout)
    const int tid  = threadIdx.x;
    const int wv   = tid >> 6;
    const int lane = tid & 63;
    const int quad = lane >> 4;
    const int l15  = lane & 15;
    const int rows0 = blockIdx.x * 128;

    f32x4 acc[2][12];
    #pragma unroll
    for (int mt = 0; mt < 2; ++mt)
        #pragma unroll
        for (int nt = 0; nt < 12; ++nt)
            acc[mt][nt] = (f32x4){0.f, 0.f, 0.f, 0.f};

    for (int kc = 0; kc < 8; ++kc) {
        __syncthreads();                // prev-iter LDS readers done
        // stage x[rows0..+128][kc*64..+64] -> xs (2048 16B-slots, 8 insts)
        #pragma unroll
        for (int j = 0; j < 8; ++j) {
            int s = j * 256 + tid;      // slot
            int r = s >> 4, up = s & 15;
            int u = up ^ (r & 15);      // global 16B-unit for this slot
            const float* gp = x + (size_t)(rows0 + r) * CC + kc * 64 + u * 4;
            g2lds16(gp, (char*)xs + (j * 256 + wv * 64) * 16);
        }
        // B-frags for both K-halves, batched (latency hides under x drain)
        bf16x8 bfr[2][12];
        #pragma unroll
        for (int h = 0; h < 2; ++h)
            #pragma unroll
            for (int nt = 0; nt < 12; ++nt)
                bfr[h][nt] = *(const bf16x8*)(wt + (size_t)((nt >> 2) * HH + (nt & 3) * 16 + l15) * CC
                                              + kc * 64 + h * 32 + quad * 8);
        __syncthreads();                // drains vmcnt(0): x staged, b-frags landed

        #pragma unroll
        for (int mt = 0; mt < 2; ++mt) {
            int row = wv * 32 + mt * 16 + l15;
            const char* rp = (const char*)xs + row * 256;
            f32x4 x0 = *(const f32x4*)(rp + (((quad * 2)     ^ l15) * 16));
            f32x4 x1 = *(const f32x4*)(rp + (((quad * 2 + 1) ^ l15) * 16));
            f32x4 x2 = *(const f32x4*)(rp + (((8 + quad * 2)     ^ l15) * 16));
            f32x4 x3 = *(const f32x4*)(rp + (((8 + quad * 2 + 1) ^ l15) * 16));
            bf16x8 a0, a1;
            #pragma unroll
            for (int j = 0; j < 4; ++j) {
                a0[j] = (bf16)x0[j]; a0[j + 4] = (bf16)x1[j];
                a1[j] = (bf16)x2[j]; a1[j + 4] = (bf16)x3[j];
            }
            #pragma unroll
            for (int nt = 0; nt < 12; ++nt) {
                acc[mt][nt] = MFMA16(a0, bfr[0][nt], acc[mt][nt]);
                acc[mt][nt] = MFMA16(a1, bfr[1][nt], acc[mt][nt]);
            }
        }
    }

    const float scale = 0.044194173824159216f;  // 512^-0.5, folded into q
    #pragma unroll
    for (int mt = 0; mt < 2; ++mt) {
        int gt = rows0 + wv * 32 + mt * 16 + quad * 4;   // + r
        #pragma unroll
        for (int nt = 0; nt < 12; ++nt) {
            int h = (nt & 3) * 16 + l15;
            int wch = nt >> 2;
            if (wch == 0) {
                #pragma unroll
                for (int r = 0; r < 4; ++r)
                    q[(gt + r) * HH + h] = (bf16)(acc[mt][nt][r] * scale);
            } else if (wch == 1) {
                #pragma unroll
                for (int r = 0; r < 4; ++r)
                    k[(gt + r) * HH + h] = (bf16)(acc[mt][nt][r]);
            } else {
                int bb = gt >> 8;
                int tloc = gt & 255;
                bf16x4 pv;
                #pragma unroll
                for (int r = 0; r < 4; ++r) pv[r] = (bf16)(acc[mt][nt][r]);
                *(bf16x4*)(&vt[(bb * HH + h) * TT + tloc]) = pv;
            }
        }
    }
}

// ---------------------------------------------------------------------------
// K2: causal attention, one block per batch (grid 256 x 256 thr, 1 block/CU).
// Q,K,V^T all DMA-staged into XOR-swizzled LDS once (96 KB, one barrier);
// the whole attention then runs from LDS. Wave wv owns row-tiles
// {wv, 7-wv, 8+wv, 15-wv} (balanced causal cost). Transposed-S formulation
// (C-layout col = qrow), softmax stats via 2 shuffles, P^T via pbuf LDS.
// ---------------------------------------------------------------------------
__global__ __launch_bounds__(256) void attn(const bf16* __restrict__ q,
                                            const bf16* __restrict__ k,
                                            const bf16* __restrict__ vt,
                                            float* __restrict__ out) {
    __shared__ bf16 qs[256 * 64];       // 32 KB, unit u of row r at u^(r&7)
    __shared__ bf16 ks[256 * 64];       // 32 KB, same swizzle
    __shared__ bf16 vs[64 * 256];       // 32 KB, unit u of row r at u^(r&31)
    __shared__ bf16 pbuf[4][16 * 264];  // 33 KB, per-wave P^T
    const int tid  = threadIdx.x;
    const int wv   = tid >> 6;
    const int lane = tid & 63;
    const int quad = lane >> 4;
    const int l15  = lane & 15;
    const int b    = blockIdx.x;

    // ---- stage q,k (8 units/row) and vt (32 units/row): 24 insts/wave ----
    #pragma unroll
    for (int j = 0; j < 8; ++j) {
        int c = wv * 8 + j;             // chunk 0..31 (64 slots each)
        int s = c * 64 + lane;
        {   // qs / ks
            int r = s >> 3, up = s & 7, u = up ^ (r & 7);
            const bf16* gq = q + ((size_t)b * TT + r) * HH + u * 8;
            const bf16* gk = k + ((size_t)b * TT + r) * HH + u * 8;
            g2lds16(gq, (char*)qs + c * 1024);
            g2lds16(gk, (char*)ks + c * 1024);
        }
        {   // vs
            int r = s >> 5, up = s & 31, u = up ^ (r & 31);
            const bf16* gv = vt + ((size_t)b * HH + r) * TT + u * 8;
            g2lds16(gv, (char*)vs + c * 1024);
        }
    }
    __syncthreads();                    // drains all DMA

    bf16* pb = &pbuf[wv][0];
    const int l7 = l15 & 7;

    #pragma unroll
    for (int ti = 0; ti < 4; ++ti) {
        const int rt = (ti == 0) ? wv : (ti == 1) ? (7 - wv) : (ti == 2) ? (8 + wv) : (15 - wv);
        const int rowbase = rt * 16;
        const int ctmax = rt;

        // Q B-frags from LDS
        const int qr = rowbase + l15;
        const char* qp = (const char*)qs + qr * 128;
        bf16x8 bq0 = *(const bf16x8*)(qp + ((quad ^ l7) * 16));
        bf16x8 bq1 = *(const bf16x8*)(qp + (((4 + quad) ^ l7) * 16));

        // Phase 1: S^T tiles
        f32x4 sv[16];
        #pragma unroll
        for (int ct = 0; ct < 16; ++ct) {
            if (ct <= ctmax) {          // wave-uniform
                const char* kp = (const char*)ks + (ct * 16 + l15) * 128;
                bf16x8 k0 = *(const bf16x8*)(kp + ((quad ^ l7) * 16));
                bf16x8 k1 = *(const bf16x8*)(kp + (((4 + quad) ^ l7) * 16));
                f32x4 a = (f32x4){0.f, 0.f, 0.f, 0.f};
                a = MFMA16(k0, bq0, a);
                a = MFMA16(k1, bq1, a);
                int t = rowbase + l15;
                #pragma unroll
                for (int r = 0; r < 4; ++r) {
                    int s = ct * 16 + quad * 4 + r;
                    sv[ct][r] = (s <= t) ? a[r] : -3.0e38f;
                }
            }
        }

        // Phase 2: row max
        float mx = -3.0e38f;
        #pragma unroll
        for (int ct = 0; ct < 16; ++ct)
            if (ct <= ctmax) {
                #pragma unroll
                for (int r = 0; r < 4; ++r) mx = fmaxf(mx, sv[ct][r]);
            }
        mx = fmaxf(mx, __shfl_xor(mx, 16));
        mx = fmaxf(mx, __shfl_xor(mx, 32));

        // Phase 3: exp + batched P^T writes
        float sm = 0.f;
        #pragma unroll
        for (int ct = 0; ct < 16; ++ct) {
            if (ct <= ctmax) {
                bf16x4 ev;
                #pragma unroll
                for (int r = 0; r < 4; ++r) {
                    float e = __expf(sv[ct][r] - mx);
                    sm += e;
                    ev[r] = (bf16)e;
                }
                *(bf16x4*)(&pb[l15 * 264 + ct * 16 + quad * 4]) = ev;
            }
        }
        if (!(ctmax & 1)) {             // zero dead half of last 32-chunk
            int ctz = ctmax + 1;
            *(bf16x4*)(&pb[l15 * 264 + ctz * 16 + quad * 4]) =
                (bf16x4){(bf16)0.f, (bf16)0.f, (bf16)0.f, (bf16)0.f};
        }
        sm += __shfl_xor(sm, 16);
        sm += __shfl_xor(sm, 32);
        asm volatile("" ::: "memory");  // keep ds_reads after ds_writes

        // Phase 4: PV from LDS
        f32x4 o[4];
        #pragma unroll
        for (int ht = 0; ht < 4; ++ht) o[ht] = (f32x4){0.f, 0.f, 0.f, 0.f};
        #pragma unroll
        for (int ks2 = 0; ks2 < 8; ++ks2) {
            if (ks2 <= (ctmax >> 1)) {  // wave-uniform
                bf16x8 pf = *(const bf16x8*)(&pb[l15 * 264 + ks2 * 32 + quad * 8]);
                #pragma unroll
                for (int ht = 0; ht < 4; ++ht) {
                    int vr = ht * 16 + l15;
                    bf16x8 vf = *(const bf16x8*)((const char*)vs + vr * 512
                                                 + (((ks2 * 4 + quad) ^ (vr & 31)) * 16));
                    o[ht] = MFMA16(vf, pf, o[ht]);
                }
            }
        }

        // Epilogue: normalize + packed fp32 stores (O^T: col=l15=qrow)
        float rinv = 1.0f / sm;
        int t = rowbase + l15;
        #pragma unroll
        for (int ht = 0; ht < 4; ++ht) {
            f32x4 ov;
            #pragma unroll
            for (int r = 0; r < 4; ++r) ov[r] = o[ht][r] * rinv;
            *(f32x4*)(&out[((size_t)b * TT + t) * HH + ht * 16 + quad * 4]) = ov;
        }
        asm volatile("" ::: "memory");  // pbuf reuse next tile: keep order
    }
}

// ---------------------------------------------------------------------------
extern "C" void kernel_launch(void* const* d_in, const int* in_sizes, int n_in,
                              void* d_out, int out_size, void* d_ws, size_t ws_size,
                              hipStream_t stream) {
    const float* x  = (const float*)d_in[0];
    const float* Wk = (const float*)d_in[1];
    const float* Wq = (const float*)d_in[2];
    const float* Wv = (const float*)d_in[3];

    bf16* ws = (bf16*)d_ws;
    bf16* wt = ws;                                   // 3 * 512*64 elems
    bf16* q  = ws + 3 * CC * HH;
    bf16* k  = q + (size_t)BB * TT * HH;
    bf16* vt = k + (size_t)BB * TT * HH;
    float* out = (float*)d_out;

    wtrans<<<dim3(32, 3), 256, 0, stream>>>(Wk, Wq, Wv, wt);
    qkv_gemm<<<dim3(512), 256, 0, stream>>>(x, wt, q, k, vt);
    attn<<<dim3(256), 256, 0, stream>>>(q, k, vt, out);
}

// Round 5
// 220.694 us; speedup vs baseline: 1.3102x; 1.0786x over previous
//
#include <hip/hip_runtime.h>

#define BB 256
#define TT 256
#define CC 512
#define HH 64

typedef __bf16 bf16;
typedef __bf16 bf16x4 __attribute__((ext_vector_type(4)));
typedef __bf16 bf16x8 __attribute__((ext_vector_type(8)));
typedef float  f32x4  __attribute__((ext_vector_type(4)));

#define MFMA16(a, b, c) __builtin_amdgcn_mfma_f32_16x16x32_bf16((a), (b), (c), 0, 0, 0)

typedef __attribute__((address_space(1))) const void cas1_void;
typedef __attribute__((address_space(3))) void as3_void;
// Fire-and-forget global->LDS DMA, 16 B/lane. LDS dest = wave-uniform base + lane*16.
__device__ __forceinline__ void g2lds16(const void* g, void* l) {
    __builtin_amdgcn_global_load_lds((cas1_void*)g, (as3_void*)l, 16, 0, 0);
}

// ---------------------------------------------------------------------------
// K0: transpose fp32 weights into bf16 wt[which][n][k]. 4 k's per thread ->
// coalesced reads (consecutive n), packed 8B writes.
// ---------------------------------------------------------------------------
__global__ __launch_bounds__(256) void wtrans(const float* __restrict__ Wk,
                                              const float* __restrict__ Wq,
                                              const float* __restrict__ Wv,
                                              bf16* __restrict__ wt) {
    int which = blockIdx.y;
    const float* W = (which == 0) ? Wq : (which == 1) ? Wk : Wv;
    int idx = blockIdx.x * 256 + threadIdx.x;   // 0..8191
    int n = idx & 63, k4 = idx >> 6;            // k4: 0..127
    bf16x4 o;
    #pragma unroll
    for (int i = 0; i < 4; ++i) o[i] = (bf16)W[(k4 * 4 + i) * HH + n];
    *(bf16x4*)(&wt[which * (CC * HH) + n * CC + k4 * 4]) = o;
}

// ---------------------------------------------------------------------------
// K1: fused QKV GEMM. 512 blocks x 256 thr; M-tile 128, BK=64.
// BOTH operands DMA-staged into swizzled LDS each kc:
//   x (fp32, 32 KB, 8 insts)  unit u of row r at slot u^(r&15)
//   wt (bf16, 24 KB, 6 insts/wave) unit u of row n at slot u^(n&7)
// No register-landing global loads in the K-loop -> no 16-segment splinter
// traffic, wt bytes cut 4x (LDS shared across the block's 4 waves).
// ---------------------------------------------------------------------------
__global__ __launch_bounds__(256, 2) void qkv_gemm(const float* __restrict__ x,
                                                   const bf16* __restrict__ wt,
                                                   bf16* __restrict__ q,
                                                   bf16* __restrict__ k,
                                                   bf16* __restrict__ vt) {
    __shared__ float xs[128 * 64];      // 32 KB
    __shared__ bf16  wts[192 * 64];     // 24 KB; row n = 8 x 16B units, swizzled
    const int tid  = threadIdx.x;
    const int wv   = tid >> 6;
    const int lane = tid & 63;
    const int quad = lane >> 4;
    const int l15  = lane & 15;
    const int l7   = l15 & 7;
    const int rows0 = blockIdx.x * 128;

    f32x4 acc[2][12];
    #pragma unroll
    for (int mt = 0; mt < 2; ++mt)
        #pragma unroll
        for (int nt = 0; nt < 12; ++nt)
            acc[mt][nt] = (f32x4){0.f, 0.f, 0.f, 0.f};

    for (int kc = 0; kc < 8; ++kc) {
        __syncthreads();                // prev-iter LDS readers done
        // stage x[rows0..+128][kc*64..+64] -> xs (2048 16B-slots, 8 insts)
        #pragma unroll
        for (int j = 0; j < 8; ++j) {
            int s = j * 256 + tid;      // slot
            int r = s >> 4, up = s & 15;
            int u = up ^ (r & 15);      // global 16B-unit for this slot
            const float* gp = x + (size_t)(rows0 + r) * CC + kc * 64 + u * 4;
            g2lds16(gp, (char*)xs + (j * 256 + wv * 64) * 16);
        }
        // stage wt[0..192][kc*64..+64] -> wts (6 insts per wave, 8 n-rows each)
        #pragma unroll
        for (int j = 0; j < 6; ++j) {
            int n0 = wv * 48 + j * 8;
            int n  = n0 + (lane >> 3);
            int u  = (lane & 7) ^ (n & 7);
            const bf16* gp = wt + (size_t)n * CC + kc * 64 + u * 8;
            g2lds16(gp, (char*)wts + n0 * 128);
        }
        __syncthreads();                // drains vmcnt(0): both tiles staged

        #pragma unroll
        for (int mt = 0; mt < 2; ++mt) {
            int row = wv * 32 + mt * 16 + l15;
            const char* rp = (const char*)xs + row * 256;
            f32x4 x0 = *(const f32x4*)(rp + (((quad * 2)     ^ l15) * 16));
            f32x4 x1 = *(const f32x4*)(rp + (((quad * 2 + 1) ^ l15) * 16));
            f32x4 x2 = *(const f32x4*)(rp + (((8 + quad * 2)     ^ l15) * 16));
            f32x4 x3 = *(const f32x4*)(rp + (((8 + quad * 2 + 1) ^ l15) * 16));
            bf16x8 a0, a1;
            #pragma unroll
            for (int j = 0; j < 4; ++j) {
                a0[j] = (bf16)x0[j]; a0[j + 4] = (bf16)x1[j];
                a1[j] = (bf16)x2[j]; a1[j + 4] = (bf16)x3[j];
            }
            #pragma unroll
            for (int nt = 0; nt < 12; ++nt) {
                int n = (nt >> 2) * 64 + (nt & 3) * 16 + l15;   // n&7 == l7
                const char* np = (const char*)wts + n * 128;
                bf16x8 b0 = *(const bf16x8*)(np + ((quad ^ l7) * 16));
                bf16x8 b1 = *(const bf16x8*)(np + (((4 + quad) ^ l7) * 16));
                acc[mt][nt] = MFMA16(a0, b0, acc[mt][nt]);
                acc[mt][nt] = MFMA16(a1, b1, acc[mt][nt]);
            }
        }
    }

    const float scale = 0.044194173824159216f;  // 512^-0.5, folded into q
    #pragma unroll
    for (int mt = 0; mt < 2; ++mt) {
        int gt = rows0 + wv * 32 + mt * 16 + quad * 4;   // + r
        #pragma unroll
        for (int nt = 0; nt < 12; ++nt) {
            int h = (nt & 3) * 16 + l15;
            int wch = nt >> 2;
            if (wch == 0) {
                #pragma unroll
                for (int r = 0; r < 4; ++r)
                    q[(gt + r) * HH + h] = (bf16)(acc[mt][nt][r] * scale);
            } else if (wch == 1) {
                #pragma unroll
                for (int r = 0; r < 4; ++r)
                    k[(gt + r) * HH + h] = (bf16)(acc[mt][nt][r]);
            } else {
                int bb = gt >> 8;
                int tloc = gt & 255;
                bf16x4 pv;
                #pragma unroll
                for (int r = 0; r < 4; ++r) pv[r] = (bf16)(acc[mt][nt][r]);
                *(bf16x4*)(&vt[(bb * HH + h) * TT + tloc]) = pv;
            }
        }
    }
}

// ---------------------------------------------------------------------------
// K2: causal attention, one block per batch (grid 256 x 256 thr, 1 block/CU).
// Q,K,V^T all DMA-staged into XOR-swizzled LDS once (96 KB, one barrier);
// the whole attention then runs from LDS. Wave wv owns row-tiles
// {wv, 7-wv, 8+wv, 15-wv} (balanced causal cost). Transposed-S formulation
// (C-layout col = qrow), softmax stats via 2 shuffles, P^T via pbuf LDS.
// ---------------------------------------------------------------------------
__global__ __launch_bounds__(256) void attn(const bf16* __restrict__ q,
                                            const bf16* __restrict__ k,
                                            const bf16* __restrict__ vt,
                                            float* __restrict__ out) {
    __shared__ bf16 qs[256 * 64];       // 32 KB, unit u of row r at u^(r&7)
    __shared__ bf16 ks[256 * 64];       // 32 KB, same swizzle
    __shared__ bf16 vs[64 * 256];       // 32 KB, unit u of row r at u^(r&31)
    __shared__ bf16 pbuf[4][16 * 264];  // 33 KB, per-wave P^T
    const int tid  = threadIdx.x;
    const int wv   = tid >> 6;
    const int lane = tid & 63;
    const int quad = lane >> 4;
    const int l15  = lane & 15;
    const int b    = blockIdx.x;

    // ---- stage q,k (8 units/row) and vt (32 units/row): 24 insts/wave ----
    #pragma unroll
    for (int j = 0; j < 8; ++j) {
        int c = wv * 8 + j;             // chunk 0..31 (64 slots each)
        int s = c * 64 + lane;
        {   // qs / ks
            int r = s >> 3, up = s & 7, u = up ^ (r & 7);
            const bf16* gq = q + ((size_t)b * TT + r) * HH + u * 8;
            const bf16* gk = k + ((size_t)b * TT + r) * HH + u * 8;
            g2lds16(gq, (char*)qs + c * 1024);
            g2lds16(gk, (char*)ks + c * 1024);
        }
        {   // vs
            int r = s >> 5, up = s & 31, u = up ^ (r & 31);
            const bf16* gv = vt + ((size_t)b * HH + r) * TT + u * 8;
            g2lds16(gv, (char*)vs + c * 1024);
        }
    }
    __syncthreads();                    // drains all DMA

    bf16* pb = &pbuf[wv][0];
    const int l7 = l15 & 7;

    #pragma unroll
    for (int ti = 0; ti < 4; ++ti) {
        const int rt = (ti == 0) ? wv : (ti == 1) ? (7 - wv) : (ti == 2) ? (8 + wv) : (15 - wv);
        const int rowbase = rt * 16;
        const int ctmax = rt;

        // Q B-frags from LDS
        const int qr = rowbase + l15;
        const char* qp = (const char*)qs + qr * 128;
        bf16x8 bq0 = *(const bf16x8*)(qp + ((quad ^ l7) * 16));
        bf16x8 bq1 = *(const bf16x8*)(qp + (((4 + quad) ^ l7) * 16));

        // Phase 1: S^T tiles
        f32x4 sv[16];
        #pragma unroll
        for (int ct = 0; ct < 16; ++ct) {
            if (ct <= ctmax) {          // wave-uniform
                const char* kp = (const char*)ks + (ct * 16 + l15) * 128;
                bf16x8 k0 = *(const bf16x8*)(kp + ((quad ^ l7) * 16));
                bf16x8 k1 = *(const bf16x8*)(kp + (((4 + quad) ^ l7) * 16));
                f32x4 a = (f32x4){0.f, 0.f, 0.f, 0.f};
                a = MFMA16(k0, bq0, a);
                a = MFMA16(k1, bq1, a);
                int t = rowbase + l15;
                #pragma unroll
                for (int r = 0; r < 4; ++r) {
                    int s = ct * 16 + quad * 4 + r;
                    sv[ct][r] = (s <= t) ? a[r] : -3.0e38f;
                }
            }
        }

        // Phase 2: row max
        float mx = -3.0e38f;
        #pragma unroll
        for (int ct = 0; ct < 16; ++ct)
            if (ct <= ctmax) {
                #pragma unroll
                for (int r = 0; r < 4; ++r) mx = fmaxf(mx, sv[ct][r]);
            }
        mx = fmaxf(mx, __shfl_xor(mx, 16));
        mx = fmaxf(mx, __shfl_xor(mx, 32));

        // Phase 3: exp + batched P^T writes
        float sm = 0.f;
        #pragma unroll
        for (int ct = 0; ct < 16; ++ct) {
            if (ct <= ctmax) {
                bf16x4 ev;
                #pragma unroll
                for (int r = 0; r < 4; ++r) {
                    float e = __expf(sv[ct][r] - mx);
                    sm += e;
                    ev[r] = (bf16)e;
                }
                *(bf16x4*)(&pb[l15 * 264 + ct * 16 + quad * 4]) = ev;
            }
        }
        if (!(ctmax & 1)) {             // zero dead half of last 32-chunk
            int ctz = ctmax + 1;
            *(bf16x4*)(&pb[l15 * 264 + ctz * 16 + quad * 4]) =
                (bf16x4){(bf16)0.f, (bf16)0.f, (bf16)0.f, (bf16)0.f};
        }
        sm += __shfl_xor(sm, 16);
        sm += __shfl_xor(sm, 32);
        asm volatile("" ::: "memory");  // keep ds_reads after ds_writes

        // Phase 4: PV from LDS
        f32x4 o[4];
        #pragma unroll
        for (int ht = 0; ht < 4; ++ht) o[ht] = (f32x4){0.f, 0.f, 0.f, 0.f};
        #pragma unroll
        for (int ks2 = 0; ks2 < 8; ++ks2) {
            if (ks2 <= (ctmax >> 1)) {  // wave-uniform
                bf16x8 pf = *(const bf16x8*)(&pb[l15 * 264 + ks2 * 32 + quad * 8]);
                #pragma unroll
                for (int ht = 0; ht < 4; ++ht) {
                    int vr = ht * 16 + l15;
                    bf16x8 vf = *(const bf16x8*)((const char*)vs + vr * 512
                                                 + (((ks2 * 4 + quad) ^ (vr & 31)) * 16));
                    o[ht] = MFMA16(vf, pf, o[ht]);
                }
            }
        }

        // Epilogue: normalize + packed fp32 stores (O^T: col=l15=qrow)
        float rinv = 1.0f / sm;
        int t = rowbase + l15;
        #pragma unroll
        for (int ht = 0; ht < 4; ++ht) {
            f32x4 ov;
            #pragma unroll
            for (int r = 0; r < 4; ++r) ov[r] = o[ht][r] * rinv;
            *(f32x4*)(&out[((size_t)b * TT + t) * HH + ht * 16 + quad * 4]) = ov;
        }
        asm volatile("" ::: "memory");  // pbuf reuse next tile: keep order
    }
}

// ---------------------------------------------------------------------------
extern "C" void kernel_launch(void* const* d_in, const int* in_sizes, int n_in,
                              void* d_out, int out_size, void* d_ws, size_t ws_size,
                              hipStream_t stream) {
    const float* x  = (const float*)d_in[0];
    const float* Wk = (const float*)d_in[1];
    const float* Wq = (const float*)d_in[2];
    const float* Wv = (const float*)d_in[3];

    bf16* ws = (bf16*)d_ws;
    bf16* wt = ws;                                   // 3 * 512*64 elems
    bf16* q  = ws + 3 * CC * HH;
    bf16* k  = q + (size_t)BB * TT * HH;
    bf16* vt = k + (size_t)BB * TT * HH;
    float* out = (float*)d_out;

    wtrans<<<dim3(32, 3), 256, 0, stream>>>(Wk, Wq, Wv, wt);
    qkv_gemm<<<dim3(512), 256, 0, stream>>>(x, wt, q, k, vt);
    attn<<<dim3(256), 256, 0, stream>>>(q, k, vt, out);
}